// Round 10
// baseline (151.624 us; speedup 1.0000x reference)
//
#include <hip/hip_runtime.h>

#define NB   32
#define NC   3
#define NH   512
#define NW   512
#define KS   25
#define HALF 12
#define NS   60
#define PLN  (NH * NW)        // 262144
#define NPL  (NB * NC)        // 96

// ---- workspace layout ----
#define HB_BYTES  ((size_t)NPL * PLN * 4)             // 100,663,296
#define WTS_OFF   HB_BYTES
#define WTS_BYTES ((size_t)4096)                      // 32 x 28 floats, padded
#define NL_OFF    (WTS_OFF + WTS_BYTES)
#define NL_BYTES  ((size_t)NB * NW * 4)
#define PK_OFF    (NL_OFF + NL_BYTES)
#define PK_BYTES  ((size_t)NB * NW * NS * 4)
#define WS_NEED   (PK_OFF + PK_BYTES)                 // ~104.7 MB

__device__ __forceinline__ float clip01(float v) { return fminf(fmaxf(v, 0.f), 1.f); }

struct PParams {
  int f1, f2, f3, f4;
  float intensity, cx, cy, rxi, ryi;
  float oy0, oy1, ox0, ox1;
  float log1ma;
  float thr_lo, thr_hi;
};

__device__ __forceinline__ PParams load_params(
    int b, const int* __restrict__ flags, const float* __restrict__ glare_u,
    const float* __restrict__ occ_u, const float* __restrict__ rain_alpha_u,
    const float* __restrict__ noise_amt_u)
{
  PParams P;
  P.f1 = flags[b * 5 + 1] > 0;
  P.f2 = flags[b * 5 + 2] > 0;
  P.f3 = flags[b * 5 + 3] > 0;
  P.f4 = flags[b * 5 + 4] > 0;
  float g0 = glare_u[b * 5 + 0], g1 = glare_u[b * 5 + 1], g2 = glare_u[b * 5 + 2],
        g3 = glare_u[b * 5 + 3], g4 = glare_u[b * 5 + 4];
  P.intensity = 0.4f + 0.5f * g0;
  P.rxi = 1.f / ((0.1f + 0.25f * g1) * 256.f);
  P.ryi = 1.f / ((0.1f + 0.25f * g2) * 256.f);
  P.cx = (0.2f + 0.6f * g3) * 512.f;
  P.cy = (0.2f + 0.6f * g4) * 512.f;
  float o0 = occ_u[b * 4 + 0], o1 = occ_u[b * 4 + 1],
        o2 = occ_u[b * 4 + 2], o3 = occ_u[b * 4 + 3];
  float ph = floorf(512.f * (0.1f + 0.3f * o0));
  float pw = floorf(512.f * (0.1f + 0.3f * o1));
  P.oy0 = floorf(o2 * (512.f - ph)); P.oy1 = P.oy0 + ph;
  P.ox0 = floorf(o3 * (512.f - pw)); P.ox1 = P.ox0 + pw;
  P.log1ma = log2f(1.f - (0.15f + 0.35f * rain_alpha_u[b]));
  float half_amt = 0.5f * (0.01f + 0.07f * noise_amt_u[b]);
  P.thr_lo = half_amt; P.thr_hi = 1.f - half_amt;
  return P;
}

// ---- prep: rain column lists (blocks 0..63) + per-sample blur weights (block 64) ----
__global__ void prep_kernel(const float* __restrict__ rain_u,
                            const float* __restrict__ rain_n_u,
                            const float* __restrict__ sigma_u,
                            int* __restrict__ nlist,
                            unsigned* __restrict__ packed,
                            float* __restrict__ wts)
{
  if (blockIdx.x == 64) {
    int b = threadIdx.x;
    if (b < NB) {
      float sig = 1.f + 3.f * sigma_u[b];
      float ninv = -1.f / (2.f * sig * sig);
      float w[KS]; float s = 0.f;
      #pragma unroll
      for (int j = 0; j < KS; ++j) {
        float d = (float)j - 12.f;
        w[j] = __expf(d * d * ninv);
        s += w[j];
      }
      float inv = 1.f / s;
      #pragma unroll
      for (int j = 0; j < KS; ++j) wts[b * 28 + j] = w[j] * inv;
    }
    return;
  }
  int t = blockIdx.x * 256 + threadIdx.x;      // [0, 32*512)
  if (t >= NB * NW) return;
  int b = t >> 9, wcol = t & 511;
  float n = floorf(20.f + 41.f * rain_n_u[b]);
  float wf = (float)wcol;
  int cnt = 0;
  for (int s = 0; s < NS; ++s) {
    if ((float)s < n) {
      float xc = floorf(rain_u[(b * NS + s) * 3 + 0] * 512.f);
      if (wf >= xc - 1.f && wf <= xc) {
        float y0 = floorf(rain_u[(b * NS + s) * 3 + 1] * 256.f);
        float y1 = 256.f + floorf(rain_u[(b * NS + s) * 3 + 2] * 256.f);
        packed[t * NS + cnt] = (((unsigned)y0) << 16) | (unsigned)y1;
        ++cnt;
      }
    }
  }
  nlist[t] = cnt;
}

// ---- K1: H-blur row streamer. 8 rows per block, 4 row-pair iterations per
// thread: amortizes the 25 scalar weight loads + params over 4x work and
// keeps ~14 float4 in flight per thread (r9: 2 rows/block -> 1.3us blocks
// dominated by two serial latency rounds). Interior threads branch-free. ----
__global__ __launch_bounds__(256, 4)
void hblur_kernel(const float* __restrict__ x, const int* __restrict__ flags,
                  const float* __restrict__ wts, float* __restrict__ hb)
{
  const int b = blockIdx.z;
  if (flags[b * 5] <= 0) return;               // non-blur sample: nothing to do
  const int ch = blockIdx.y;
  const int tid = threadIdx.x;
  const int r0 = blockIdx.x << 3;              // 8 rows per block

  float w[KS];
  const float* wp = wts + b * 28;              // sample-uniform -> scalar loads
  #pragma unroll
  for (int j = 0; j < KS; ++j) w[j] = wp[j];

  const size_t plane = (size_t)(b * NC + ch) * PLN;

  if (tid < 244) {
    // interior quads 3..124; waves 0-2 fully uniform, branch-free
    const int rofs = (tid >= 122);
    const int q = (tid >= 122 ? tid - 122 : tid) + 3;
    const int gx0 = q << 2;
    #pragma unroll 2
    for (int i = 0; i < 4; ++i) {
      int row = r0 + 2 * i + rofs;
      const float* rowp = x + plane + (size_t)row * NW;
      float win[28];
      #pragma unroll
      for (int j = 0; j < 7; ++j) {
        float4 v = *reinterpret_cast<const float4*>(rowp + gx0 - HALF + 4 * j);
        win[4 * j + 0] = v.x; win[4 * j + 1] = v.y;
        win[4 * j + 2] = v.z; win[4 * j + 3] = v.w;
      }
      float a0 = 0.f, a1 = 0.f, a2 = 0.f, a3 = 0.f;
      #pragma unroll
      for (int t = 0; t < KS; ++t) {
        float wt = w[t];
        a0 = fmaf(wt, win[t + 0], a0);
        a1 = fmaf(wt, win[t + 1], a1);
        a2 = fmaf(wt, win[t + 2], a2);
        a3 = fmaf(wt, win[t + 3], a3);
      }
      *reinterpret_cast<float4*>(hb + plane + (size_t)row * NW + gx0) =
          make_float4(a0, a1, a2, a3);
    }
  } else {
    // 12 edge quads per row-pair, handled by wave 3 only
    const int e = tid - 244;                   // 0..11
    const int rofs = (e >= 6);
    const int es = (e >= 6 ? e - 6 : e);       // 0..5
    const int q = (es < 3) ? es : (122 + es);  // {0,1,2,125,126,127}
    const int gx0 = q << 2;
    for (int i = 0; i < 4; ++i) {
      int row = r0 + 2 * i + rofs;
      const float* rowp = x + plane + (size_t)row * NW;
      float win[28];
      #pragma unroll
      for (int j = 0; j < 28; ++j) {
        int gx = gx0 - HALF + j;
        win[j] = ((unsigned)gx < (unsigned)NW) ? rowp[gx] : 0.f;
      }
      float a0 = 0.f, a1 = 0.f, a2 = 0.f, a3 = 0.f;
      #pragma unroll
      for (int t = 0; t < KS; ++t) {
        float wt = w[t];
        a0 = fmaf(wt, win[t + 0], a0);
        a1 = fmaf(wt, win[t + 1], a1);
        a2 = fmaf(wt, win[t + 2], a2);
        a3 = fmaf(wt, win[t + 3], a3);
      }
      *reinterpret_cast<float4*>(hb + plane + (size_t)row * NW + gx0) =
          make_float4(a0, a1, a2, a3);
    }
  }
}

// ---- chain on a 4-col x 8-row quad block (all static indexing) ----
__device__ __forceinline__ void chain_quad(
    float a[8][4], const PParams& P, int b, int gx0, int gy0,
    const float* __restrict__ np_plane, const int* __restrict__ nlist,
    const unsigned* __restrict__ packed, float* __restrict__ op_plane)
{
  if (P.f1) {
    float dx2[4];
    #pragma unroll
    for (int c = 0; c < 4; ++c) {
      float dx = ((float)(gx0 + c) - P.cx) * P.rxi;
      dx2[c] = dx * dx;
    }
    #pragma unroll
    for (int k = 0; k < 8; ++k) {
      float dy = ((float)(gy0 + k) - P.cy) * P.ryi;
      float dy2 = dy * dy;
      #pragma unroll
      for (int c = 0; c < 4; ++c) {
        float g = __expf(-(dx2[c] + dy2));
        a[k][c] = clip01(a[k][c] + P.intensity * g);
      }
    }
  }
  if (P.f2) {
    #pragma unroll
    for (int c = 0; c < 4; ++c) {
      float fx = (float)(gx0 + c);
      if (fx >= P.ox0 && fx < P.ox1) {
        #pragma unroll
        for (int k = 0; k < 8; ++k) {
          float fy = (float)(gy0 + k);
          if (fy >= P.oy0 && fy < P.oy1) a[k][c] = 0.f;
        }
      }
    }
  }
  if (P.f3) {
    #pragma unroll
    for (int c = 0; c < 4; ++c) {
      int base = b * NW + gx0 + c;
      int n = nlist[base];
      if (n > 0) {
        float cnt[8];
        #pragma unroll
        for (int k = 0; k < 8; ++k) cnt[k] = 0.f;
        for (int j = 0; j < n; ++j) {
          unsigned p = packed[base * NS + j];
          float y0 = (float)(p >> 16), y1 = (float)(p & 0xffffu);
          #pragma unroll
          for (int k = 0; k < 8; ++k) {
            float fy = (float)(gy0 + k);
            cnt[k] += (fy >= y0 && fy < y1) ? 1.f : 0.f;
          }
        }
        #pragma unroll
        for (int k = 0; k < 8; ++k) {
          if (cnt[k] != 0.f) {
            float d = exp2f(cnt[k] * P.log1ma);
            a[k][c] = clip01(a[k][c] * d + (1.f - d));
          }
        }
      }
    }
  }
  if (P.f4) {
    #pragma unroll
    for (int k = 0; k < 8; ++k) {
      float4 nv = *reinterpret_cast<const float4*>(
          np_plane + (size_t)(gy0 + k) * NW + gx0);
      a[k][0] = (nv.x < P.thr_lo) ? 0.f : ((nv.x > P.thr_hi) ? 1.f : a[k][0]);
      a[k][1] = (nv.y < P.thr_lo) ? 0.f : ((nv.y > P.thr_hi) ? 1.f : a[k][1]);
      a[k][2] = (nv.z < P.thr_lo) ? 0.f : ((nv.z > P.thr_hi) ? 1.f : a[k][2]);
      a[k][3] = (nv.w < P.thr_lo) ? 0.f : ((nv.w > P.thr_hi) ? 1.f : a[k][3]);
    }
  }
  #pragma unroll
  for (int k = 0; k < 8; ++k)
    *reinterpret_cast<float4*>(op_plane + (size_t)(gy0 + k) * NW + gx0) =
        make_float4(a[k][0], a[k][1], a[k][2], a[k][3]);
}

// ---- K2: V-blur + chain streamer. NO block swizzle: r9's XCD-chunk swizzle
// gave each XCD a contiguous run of planes = 4 whole samples; per-sample
// cost varies ~4x with flags, so whole XCDs idled (occupancy stuck ~29%).
// Default round-robin spreads every plane across all 8 XCDs -> balanced;
// hb halo reads are L3-served (hb is L3-resident) so locality loss is nil. ----
__global__ __launch_bounds__(256, 4)
void vchain_kernel(const float* __restrict__ x, const float* __restrict__ hb,
                   const float* __restrict__ wts,
                   const float* __restrict__ glare_u, const float* __restrict__ occ_u,
                   const float* __restrict__ rain_alpha_u,
                   const float* __restrict__ noise_u, const float* __restrict__ noise_amt_u,
                   const int* __restrict__ flags,
                   const int* __restrict__ nlist, const unsigned* __restrict__ packed,
                   float* __restrict__ out)
{
  const int t = blockIdx.x;                   // identity mapping (no swizzle)
  const int strip = t & 31;                   // 16-row strip within plane
  const int pl = t >> 5;                      // plane 0..95
  const int b = pl / 3;
  const int tid = threadIdx.x;
  const int gy0 = strip * 16 + ((tid >> 7) << 3);   // wave-uniform
  const int gx0 = (tid & 127) << 2;

  const int f0 = flags[b * 5] > 0;
  PParams P = load_params(b, flags, glare_u, occ_u, rain_alpha_u, noise_amt_u);
  const size_t plane = (size_t)pl * PLN;

  float a[8][4];
  if (f0) {
    float w[KS];
    const float* wp = wts + b * 28;
    #pragma unroll
    for (int j = 0; j < KS; ++j) w[j] = wp[j];
    #pragma unroll
    for (int k = 0; k < 8; ++k) {
      a[k][0] = 0.f; a[k][1] = 0.f; a[k][2] = 0.f; a[k][3] = 0.f;
    }
    if (gy0 >= 16 && gy0 <= 488) {
      // interior: all 32 halo rows in-bounds -> straight-line 32 float4 loads
      const float* hp0 = hb + plane + (size_t)(gy0 - HALF) * NW + gx0;
      #pragma unroll
      for (int m = 0; m < 32; ++m) {
        float4 v = *reinterpret_cast<const float4*>(hp0 + (size_t)m * NW);
        #pragma unroll
        for (int k = 0; k < 8; ++k) {
          int wi = m - k;                     // compile-time after unroll
          if (wi >= 0 && wi <= 24) {
            float wt = w[wi];
            a[k][0] = fmaf(wt, v.x, a[k][0]);
            a[k][1] = fmaf(wt, v.y, a[k][1]);
            a[k][2] = fmaf(wt, v.z, a[k][2]);
            a[k][3] = fmaf(wt, v.w, a[k][3]);
          }
        }
      }
    } else {
      // y-edge sub-strips (4 of 64): guarded per-row
      const float* hp = hb + plane + gx0;
      #pragma unroll
      for (int m = 0; m < 32; ++m) {
        int gy = gy0 - HALF + m;
        if ((unsigned)gy < (unsigned)NH) {
          float4 v = *reinterpret_cast<const float4*>(hp + (size_t)gy * NW);
          #pragma unroll
          for (int k = 0; k < 8; ++k) {
            int wi = m - k;
            if (wi >= 0 && wi <= 24) {
              float wt = w[wi];
              a[k][0] = fmaf(wt, v.x, a[k][0]);
              a[k][1] = fmaf(wt, v.y, a[k][1]);
              a[k][2] = fmaf(wt, v.z, a[k][2]);
              a[k][3] = fmaf(wt, v.w, a[k][3]);
            }
          }
        }
      }
    }
    #pragma unroll
    for (int k = 0; k < 8; ++k) {
      a[k][0] = clip01(a[k][0]); a[k][1] = clip01(a[k][1]);
      a[k][2] = clip01(a[k][2]); a[k][3] = clip01(a[k][3]);
    }
  } else {
    const float* xp = x + plane + gx0;
    #pragma unroll
    for (int k = 0; k < 8; ++k) {
      float4 v = *reinterpret_cast<const float4*>(xp + (size_t)(gy0 + k) * NW);
      a[k][0] = v.x; a[k][1] = v.y; a[k][2] = v.z; a[k][3] = v.w;
    }
  }
  chain_quad(a, P, b, gx0, gy0, noise_u + plane, nlist, packed, out + plane);
}

// ---- fallback (ws too small): r3's fused single kernel, no lists ----
__global__ __launch_bounds__(256, 4)
void fallback_kernel(const float* __restrict__ x, const float* __restrict__ sigma_u,
                     const float* __restrict__ glare_u, const float* __restrict__ occ_u,
                     const float* __restrict__ rain_u, const float* __restrict__ rain_n_u,
                     const float* __restrict__ rain_alpha_u, const float* __restrict__ noise_u,
                     const float* __restrict__ noise_amt_u, const int* __restrict__ flags,
                     float* __restrict__ out)
{
  const int b = blockIdx.z, ch = blockIdx.y;
  const int ty0 = (blockIdx.x >> 3) * 64, tx0 = (blockIdx.x & 7) * 64;
  const int tid = threadIdx.x;
  const int f0 = flags[b * 5] > 0;
  PParams P = load_params(b, flags, glare_u, occ_u, rain_alpha_u, noise_amt_u);
  const float nrain = floorf(20.f + 41.f * rain_n_u[b]);
  const size_t plane = (size_t)(b * NC + ch) * PLN;
  const float* xp = x + plane;
  const float* np = noise_u + plane;
  float* op = out + plane;

  __shared__ __align__(16) float s_hb[88 * 64];

  float wr[KS];
  if (f0) {
    float sig = 1.f + 3.f * sigma_u[b];
    float ninv = -1.f / (2.f * sig * sig);
    float s = 0.f;
    #pragma unroll
    for (int t = 0; t < KS; ++t) {
      float d = (float)t - 12.f;
      wr[t] = __expf(d * d * ninv); s += wr[t];
    }
    float inv = 1.f / s;
    #pragma unroll
    for (int t = 0; t < KS; ++t) wr[t] *= inv;

    for (int i = tid; i < 88 * 16; i += 256) {
      int r = i >> 4, q = i & 15;
      int gy = ty0 + r - HALF;
      float a0 = 0.f, a1 = 0.f, a2 = 0.f, a3 = 0.f;
      if ((unsigned)gy < (unsigned)NH) {
        const float* rowp = xp + (size_t)gy * NW;
        int gx0 = tx0 + q * 4;
        float win[28];
        if (gx0 - HALF >= 0 && gx0 + 15 < NW) {
          #pragma unroll
          for (int j = 0; j < 7; ++j) {
            float4 v = *reinterpret_cast<const float4*>(rowp + gx0 - HALF + 4 * j);
            win[4 * j + 0] = v.x; win[4 * j + 1] = v.y;
            win[4 * j + 2] = v.z; win[4 * j + 3] = v.w;
          }
        } else {
          #pragma unroll
          for (int j = 0; j < 28; ++j) {
            int gx = gx0 - HALF + j;
            win[j] = ((unsigned)gx < (unsigned)NW) ? rowp[gx] : 0.f;
          }
        }
        #pragma unroll
        for (int t = 0; t < KS; ++t) {
          float wt = wr[t];
          a0 = fmaf(wt, win[t + 0], a0);
          a1 = fmaf(wt, win[t + 1], a1);
          a2 = fmaf(wt, win[t + 2], a2);
          a3 = fmaf(wt, win[t + 3], a3);
        }
      }
      *reinterpret_cast<float4*>(&s_hb[r * 64 + (i & 15) * 4]) =
          make_float4(a0, a1, a2, a3);
    }
    __syncthreads();
  }

  for (int i = tid; i < 512; i += 256) {
    int xq = i & 63, sy = i >> 6;
    int gx = tx0 + xq, gy0 = ty0 + sy * 8;
    float acc[8];
    if (f0) {
      float wincol[32];
      #pragma unroll
      for (int j = 0; j < 32; ++j) wincol[j] = s_hb[(sy * 8 + j) * 64 + xq];
      #pragma unroll
      for (int k = 0; k < 8; ++k) {
        float a = 0.f;
        #pragma unroll
        for (int t = 0; t < KS; ++t) a = fmaf(wr[t], wincol[k + t], a);
        acc[k] = clip01(a);
      }
    } else {
      #pragma unroll
      for (int k = 0; k < 8; ++k) acc[k] = xp[(size_t)(gy0 + k) * NW + gx];
    }
    const float fx = (float)gx;
    if (P.f1) {
      float dx = (fx - P.cx) * P.rxi;
      float dx2 = dx * dx;
      #pragma unroll
      for (int k = 0; k < 8; ++k) {
        float dy = ((float)(gy0 + k) - P.cy) * P.ryi;
        acc[k] = clip01(acc[k] + P.intensity * __expf(-(dx2 + dy * dy)));
      }
    }
    if (P.f2 && fx >= P.ox0 && fx < P.ox1) {
      #pragma unroll
      for (int k = 0; k < 8; ++k) {
        float fy = (float)(gy0 + k);
        if (fy >= P.oy0 && fy < P.oy1) acc[k] = 0.f;
      }
    }
    if (P.f3) {
      float cnt[8];
      #pragma unroll
      for (int k = 0; k < 8; ++k) cnt[k] = 0.f;
      for (int s = 0; s < NS; ++s) {
        if ((float)s < nrain) {
          float xc = floorf(rain_u[(b * NS + s) * 3 + 0] * 512.f);
          if (fx >= xc - 1.f && fx <= xc) {
            float y0 = floorf(rain_u[(b * NS + s) * 3 + 1] * 256.f);
            float y1 = 256.f + floorf(rain_u[(b * NS + s) * 3 + 2] * 256.f);
            #pragma unroll
            for (int k = 0; k < 8; ++k) {
              float fy = (float)(gy0 + k);
              cnt[k] += (fy >= y0 && fy < y1) ? 1.f : 0.f;
            }
          }
        }
      }
      #pragma unroll
      for (int k = 0; k < 8; ++k) {
        if (cnt[k] != 0.f) {
          float d = exp2f(cnt[k] * P.log1ma);
          acc[k] = clip01(acc[k] * d + (1.f - d));
        }
      }
    }
    if (P.f4) {
      #pragma unroll
      for (int k = 0; k < 8; ++k) {
        float nv = np[(size_t)(gy0 + k) * NW + gx];
        acc[k] = (nv < P.thr_lo) ? 0.f : ((nv > P.thr_hi) ? 1.f : acc[k]);
      }
    }
    #pragma unroll
    for (int k = 0; k < 8; ++k) op[(size_t)(gy0 + k) * NW + gx] = acc[k];
  }
}

extern "C" void kernel_launch(void* const* d_in, const int* in_sizes, int n_in,
                              void* d_out, int out_size, void* d_ws, size_t ws_size,
                              hipStream_t stream)
{
  const float* x            = (const float*)d_in[0];
  const float* sigma_u      = (const float*)d_in[1];
  const float* glare_u      = (const float*)d_in[2];
  const float* occ_u        = (const float*)d_in[3];
  const float* rain_u       = (const float*)d_in[4];
  const float* rain_n_u     = (const float*)d_in[5];
  const float* rain_alpha_u = (const float*)d_in[6];
  const float* noise_u      = (const float*)d_in[7];
  const float* noise_amt_u  = (const float*)d_in[8];
  const int*   flags        = (const int*)d_in[9];
  float* out = (float*)d_out;

  if (ws_size >= WS_NEED) {
    float*    hb     = (float*)d_ws;
    float*    wts    = (float*)((char*)d_ws + WTS_OFF);
    int*      nlist  = (int*)((char*)d_ws + NL_OFF);
    unsigned* packed = (unsigned*)((char*)d_ws + PK_OFF);

    prep_kernel<<<65, 256, 0, stream>>>(rain_u, rain_n_u, sigma_u, nlist, packed, wts);
    hblur_kernel<<<dim3(NH / 8, NC, NB), 256, 0, stream>>>(x, flags, wts, hb);
    vchain_kernel<<<3072, 256, 0, stream>>>(
        x, hb, wts, glare_u, occ_u, rain_alpha_u, noise_u, noise_amt_u,
        flags, nlist, packed, out);
  } else {
    dim3 grid(64, NC, NB);
    fallback_kernel<<<grid, 256, 0, stream>>>(
        x, sigma_u, glare_u, occ_u, rain_u, rain_n_u, rain_alpha_u,
        noise_u, noise_amt_u, flags, out);
  }
}

// Round 11
// 124.444 us; speedup vs baseline: 1.2184x; 1.2184x over previous
//
#include <hip/hip_runtime.h>

#define NB   32
#define NC   3
#define NH   512
#define NW   512
#define KS   25
#define HALF 12
#define NS   60
#define PLN  (NH * NW)        // 262144
#define NPL  (NB * NC)        // 96

typedef _Float16 half4 __attribute__((ext_vector_type(4)));

// ---- workspace layout (hb now fp16: 50.3 MB) ----
#define HB_BYTES  ((size_t)NPL * PLN * 2)
#define WTS_OFF   HB_BYTES
#define WTS_BYTES ((size_t)4096)
#define NL_OFF    (WTS_OFF + WTS_BYTES)
#define NL_BYTES  ((size_t)NB * NW * 4)
#define PK_OFF    (NL_OFF + NL_BYTES)
#define PK_BYTES  ((size_t)NB * NW * NS * 4)
#define WS_NEED   (PK_OFF + PK_BYTES)                 // ~54.3 MB

__device__ __forceinline__ float clip01(float v) { return fminf(fmaxf(v, 0.f), 1.f); }

struct PParams {
  int f1, f2, f3, f4;
  float intensity, cx, cy, rxi, ryi;
  float oy0, oy1, ox0, ox1;
  float log1ma;
  float thr_lo, thr_hi;
};

__device__ __forceinline__ PParams load_params(
    int b, const int* __restrict__ flags, const float* __restrict__ glare_u,
    const float* __restrict__ occ_u, const float* __restrict__ rain_alpha_u,
    const float* __restrict__ noise_amt_u)
{
  PParams P;
  P.f1 = flags[b * 5 + 1] > 0;
  P.f2 = flags[b * 5 + 2] > 0;
  P.f3 = flags[b * 5 + 3] > 0;
  P.f4 = flags[b * 5 + 4] > 0;
  float g0 = glare_u[b * 5 + 0], g1 = glare_u[b * 5 + 1], g2 = glare_u[b * 5 + 2],
        g3 = glare_u[b * 5 + 3], g4 = glare_u[b * 5 + 4];
  P.intensity = 0.4f + 0.5f * g0;
  P.rxi = 1.f / ((0.1f + 0.25f * g1) * 256.f);
  P.ryi = 1.f / ((0.1f + 0.25f * g2) * 256.f);
  P.cx = (0.2f + 0.6f * g3) * 512.f;
  P.cy = (0.2f + 0.6f * g4) * 512.f;
  float o0 = occ_u[b * 4 + 0], o1 = occ_u[b * 4 + 1],
        o2 = occ_u[b * 4 + 2], o3 = occ_u[b * 4 + 3];
  float ph = floorf(512.f * (0.1f + 0.3f * o0));
  float pw = floorf(512.f * (0.1f + 0.3f * o1));
  P.oy0 = floorf(o2 * (512.f - ph)); P.oy1 = P.oy0 + ph;
  P.ox0 = floorf(o3 * (512.f - pw)); P.ox1 = P.ox0 + pw;
  P.log1ma = log2f(1.f - (0.15f + 0.35f * rain_alpha_u[b]));
  float half_amt = 0.5f * (0.01f + 0.07f * noise_amt_u[b]);
  P.thr_lo = half_amt; P.thr_hi = 1.f - half_amt;
  return P;
}

// ---- prep: rain column lists + per-sample blur weights ----
__global__ void prep_kernel(const float* __restrict__ rain_u,
                            const float* __restrict__ rain_n_u,
                            const float* __restrict__ sigma_u,
                            int* __restrict__ nlist,
                            unsigned* __restrict__ packed,
                            float* __restrict__ wts)
{
  if (blockIdx.x == 64) {
    int b = threadIdx.x;
    if (b < NB) {
      float sig = 1.f + 3.f * sigma_u[b];
      float ninv = -1.f / (2.f * sig * sig);
      float w[KS]; float s = 0.f;
      #pragma unroll
      for (int j = 0; j < KS; ++j) {
        float d = (float)j - 12.f;
        w[j] = __expf(d * d * ninv);
        s += w[j];
      }
      float inv = 1.f / s;
      #pragma unroll
      for (int j = 0; j < KS; ++j) wts[b * 28 + j] = w[j] * inv;
    }
    return;
  }
  int t = blockIdx.x * 256 + threadIdx.x;
  if (t >= NB * NW) return;
  int b = t >> 9, wcol = t & 511;
  float n = floorf(20.f + 41.f * rain_n_u[b]);
  float wf = (float)wcol;
  int cnt = 0;
  for (int s = 0; s < NS; ++s) {
    if ((float)s < n) {
      float xc = floorf(rain_u[(b * NS + s) * 3 + 0] * 512.f);
      if (wf >= xc - 1.f && wf <= xc) {
        float y0 = floorf(rain_u[(b * NS + s) * 3 + 1] * 256.f);
        float y1 = 256.f + floorf(rain_u[(b * NS + s) * 3 + 2] * 256.f);
        packed[t * NS + cnt] = (((unsigned)y0) << 16) | (unsigned)y1;
        ++cnt;
      }
    }
  }
  nlist[t] = cnt;
}

// ---- chain on a 4-col x KR-row quad block ----
template<int KR>
__device__ __forceinline__ void chain_quadN(
    float (&a)[KR][4], const PParams& P, int b, int gx0, int gy0,
    const float* __restrict__ np_plane, const int* __restrict__ nlist,
    const unsigned* __restrict__ packed, float* __restrict__ op_plane)
{
  if (P.f1) {
    float dx2[4];
    #pragma unroll
    for (int c = 0; c < 4; ++c) {
      float dx = ((float)(gx0 + c) - P.cx) * P.rxi;
      dx2[c] = dx * dx;
    }
    #pragma unroll
    for (int k = 0; k < KR; ++k) {
      float dy = ((float)(gy0 + k) - P.cy) * P.ryi;
      float dy2 = dy * dy;
      #pragma unroll
      for (int c = 0; c < 4; ++c) {
        float g = __expf(-(dx2[c] + dy2));
        a[k][c] = clip01(a[k][c] + P.intensity * g);
      }
    }
  }
  if (P.f2) {
    #pragma unroll
    for (int c = 0; c < 4; ++c) {
      float fx = (float)(gx0 + c);
      if (fx >= P.ox0 && fx < P.ox1) {
        #pragma unroll
        for (int k = 0; k < KR; ++k) {
          float fy = (float)(gy0 + k);
          if (fy >= P.oy0 && fy < P.oy1) a[k][c] = 0.f;
        }
      }
    }
  }
  if (P.f3) {
    #pragma unroll
    for (int c = 0; c < 4; ++c) {
      int base = b * NW + gx0 + c;
      int n = nlist[base];
      if (n > 0) {
        float cnt[KR];
        #pragma unroll
        for (int k = 0; k < KR; ++k) cnt[k] = 0.f;
        for (int j = 0; j < n; ++j) {
          unsigned p = packed[base * NS + j];
          float y0 = (float)(p >> 16), y1 = (float)(p & 0xffffu);
          #pragma unroll
          for (int k = 0; k < KR; ++k) {
            float fy = (float)(gy0 + k);
            cnt[k] += (fy >= y0 && fy < y1) ? 1.f : 0.f;
          }
        }
        #pragma unroll
        for (int k = 0; k < KR; ++k) {
          if (cnt[k] != 0.f) {
            float d = exp2f(cnt[k] * P.log1ma);
            a[k][c] = clip01(a[k][c] * d + (1.f - d));
          }
        }
      }
    }
  }
  if (P.f4) {
    #pragma unroll
    for (int k = 0; k < KR; ++k) {
      float4 nv = *reinterpret_cast<const float4*>(
          np_plane + (size_t)(gy0 + k) * NW + gx0);
      a[k][0] = (nv.x < P.thr_lo) ? 0.f : ((nv.x > P.thr_hi) ? 1.f : a[k][0]);
      a[k][1] = (nv.y < P.thr_lo) ? 0.f : ((nv.y > P.thr_hi) ? 1.f : a[k][1]);
      a[k][2] = (nv.z < P.thr_lo) ? 0.f : ((nv.z > P.thr_hi) ? 1.f : a[k][2]);
      a[k][3] = (nv.w < P.thr_lo) ? 0.f : ((nv.w > P.thr_hi) ? 1.f : a[k][3]);
    }
  }
  #pragma unroll
  for (int k = 0; k < KR; ++k)
    *reinterpret_cast<float4*>(op_plane + (size_t)(gy0 + k) * NW + gx0) =
        make_float4(a[k][0], a[k][1], a[k][2], a[k][3]);
}

// ---- K1: blur samples -> h-blur 8 rows to fp16 hb; non-blur samples ->
// full streaming chain directly to out. Mixing latency-bound blur waves with
// pure-streaming chain waves keeps CUs fed during the whole dispatch. ----
__global__ __launch_bounds__(256, 4)
void k1_kernel(const float* __restrict__ x, const int* __restrict__ flags,
               const float* __restrict__ wts,
               const float* __restrict__ glare_u, const float* __restrict__ occ_u,
               const float* __restrict__ rain_alpha_u,
               const float* __restrict__ noise_u, const float* __restrict__ noise_amt_u,
               const int* __restrict__ nlist, const unsigned* __restrict__ packed,
               _Float16* __restrict__ hb, float* __restrict__ out)
{
  const int b = blockIdx.z, ch = blockIdx.y;
  const int tid = threadIdx.x;
  const int r0 = blockIdx.x << 3;              // 8 rows per block
  const size_t plane = (size_t)(b * NC + ch) * PLN;

  if (flags[b * 5] > 0) {
    // ---- h-blur path (fp16 output) ----
    float w[KS];
    const float* wp = wts + b * 28;
    #pragma unroll
    for (int j = 0; j < KS; ++j) w[j] = wp[j];

    if (tid < 244) {
      const int rofs = (tid >= 122);
      const int q = (tid >= 122 ? tid - 122 : tid) + 3;
      const int gx0 = q << 2;
      #pragma unroll 2
      for (int i = 0; i < 4; ++i) {
        int row = r0 + 2 * i + rofs;
        const float* rowp = x + plane + (size_t)row * NW;
        float win[28];
        #pragma unroll
        for (int j = 0; j < 7; ++j) {
          float4 v = *reinterpret_cast<const float4*>(rowp + gx0 - HALF + 4 * j);
          win[4 * j + 0] = v.x; win[4 * j + 1] = v.y;
          win[4 * j + 2] = v.z; win[4 * j + 3] = v.w;
        }
        float a0 = 0.f, a1 = 0.f, a2 = 0.f, a3 = 0.f;
        #pragma unroll
        for (int t = 0; t < KS; ++t) {
          float wt = w[t];
          a0 = fmaf(wt, win[t + 0], a0);
          a1 = fmaf(wt, win[t + 1], a1);
          a2 = fmaf(wt, win[t + 2], a2);
          a3 = fmaf(wt, win[t + 3], a3);
        }
        half4 o; o.x = (_Float16)a0; o.y = (_Float16)a1;
        o.z = (_Float16)a2; o.w = (_Float16)a3;
        *reinterpret_cast<half4*>(hb + plane + (size_t)row * NW + gx0) = o;
      }
    } else {
      const int e = tid - 244;                 // 0..11
      const int rofs = (e >= 6);
      const int es = (e >= 6 ? e - 6 : e);     // 0..5
      const int q = (es < 3) ? es : (122 + es);
      const int gx0 = q << 2;
      for (int i = 0; i < 4; ++i) {
        int row = r0 + 2 * i + rofs;
        const float* rowp = x + plane + (size_t)row * NW;
        float win[28];
        #pragma unroll
        for (int j = 0; j < 28; ++j) {
          int gx = gx0 - HALF + j;
          win[j] = ((unsigned)gx < (unsigned)NW) ? rowp[gx] : 0.f;
        }
        float a0 = 0.f, a1 = 0.f, a2 = 0.f, a3 = 0.f;
        #pragma unroll
        for (int t = 0; t < KS; ++t) {
          float wt = w[t];
          a0 = fmaf(wt, win[t + 0], a0);
          a1 = fmaf(wt, win[t + 1], a1);
          a2 = fmaf(wt, win[t + 2], a2);
          a3 = fmaf(wt, win[t + 3], a3);
        }
        half4 o; o.x = (_Float16)a0; o.y = (_Float16)a1;
        o.z = (_Float16)a2; o.w = (_Float16)a3;
        *reinterpret_cast<half4*>(hb + plane + (size_t)row * NW + gx0) = o;
      }
    }
  } else {
    // ---- non-blur: streaming chain straight to out (4 rows/thread) ----
    PParams P = load_params(b, flags, glare_u, occ_u, rain_alpha_u, noise_amt_u);
    const int gx0 = (tid & 127) << 2;
    const int gy0 = r0 + ((tid >> 7) << 2);
    float a[4][4];
    const float* xp = x + plane + gx0;
    #pragma unroll
    for (int k = 0; k < 4; ++k) {
      float4 v = *reinterpret_cast<const float4*>(xp + (size_t)(gy0 + k) * NW);
      a[k][0] = v.x; a[k][1] = v.y; a[k][2] = v.z; a[k][3] = v.w;
    }
    chain_quadN<4>(a, P, b, gx0, gy0, noise_u + plane, nlist, packed, out + plane);
  }
}

// ---- K2: v-blur + chain, blur planes only (others early-exit).
// Balanced XCD swizzle: groups of 4 adjacent strips stay on one XCD
// (halo L2 locality, r9's 78MB FETCH) but every plane is spread across
// all 8 XCDs via grp=(xcd+plane)&7 (kills r9's whole-sample-per-XCD
// imbalance). Bijective. ----
__global__ __launch_bounds__(256, 4)
void k2_kernel(const _Float16* __restrict__ hb, const float* __restrict__ wts,
               const float* __restrict__ glare_u, const float* __restrict__ occ_u,
               const float* __restrict__ rain_alpha_u,
               const float* __restrict__ noise_u, const float* __restrict__ noise_amt_u,
               const int* __restrict__ flags,
               const int* __restrict__ nlist, const unsigned* __restrict__ packed,
               float* __restrict__ out)
{
  const int lb = blockIdx.x;
  const int xcd = lb & 7, j = lb >> 3;        // assume round-robin blockIdx->XCD
  const int pl = j >> 2, sub = j & 3;         // plane 0..95, strip-in-group
  const int grp = (xcd + pl) & 7;
  const int strip = (grp << 2) | sub;         // 0..31
  const int b = pl / 3;
  if (flags[b * 5] <= 0) return;              // non-blur plane: K1 handled it

  const int tid = threadIdx.x;
  const int gy0 = strip * 16 + ((tid >> 7) << 3);   // wave-uniform
  const int gx0 = (tid & 127) << 2;
  PParams P = load_params(b, flags, glare_u, occ_u, rain_alpha_u, noise_amt_u);
  const size_t plane = (size_t)pl * PLN;

  float w[KS];
  const float* wp = wts + b * 28;
  #pragma unroll
  for (int jj = 0; jj < KS; ++jj) w[jj] = wp[jj];

  float a[8][4];
  #pragma unroll
  for (int k = 0; k < 8; ++k) {
    a[k][0] = 0.f; a[k][1] = 0.f; a[k][2] = 0.f; a[k][3] = 0.f;
  }
  if (gy0 >= 16 && gy0 <= 488) {
    // interior: straight-line 32 half4 loads (8B each -> 2 VGPRs in flight)
    const _Float16* hp0 = hb + plane + (size_t)(gy0 - HALF) * NW + gx0;
    #pragma unroll
    for (int m = 0; m < 32; ++m) {
      half4 v = *reinterpret_cast<const half4*>(hp0 + (size_t)m * NW);
      float v0 = (float)v.x, v1 = (float)v.y, v2 = (float)v.z, v3 = (float)v.w;
      #pragma unroll
      for (int k = 0; k < 8; ++k) {
        int wi = m - k;
        if (wi >= 0 && wi <= 24) {
          float wt = w[wi];
          a[k][0] = fmaf(wt, v0, a[k][0]);
          a[k][1] = fmaf(wt, v1, a[k][1]);
          a[k][2] = fmaf(wt, v2, a[k][2]);
          a[k][3] = fmaf(wt, v3, a[k][3]);
        }
      }
    }
  } else {
    const _Float16* hp = hb + plane + gx0;
    #pragma unroll
    for (int m = 0; m < 32; ++m) {
      int gy = gy0 - HALF + m;
      if ((unsigned)gy < (unsigned)NH) {
        half4 v = *reinterpret_cast<const half4*>(hp + (size_t)gy * NW);
        float v0 = (float)v.x, v1 = (float)v.y, v2 = (float)v.z, v3 = (float)v.w;
        #pragma unroll
        for (int k = 0; k < 8; ++k) {
          int wi = m - k;
          if (wi >= 0 && wi <= 24) {
            float wt = w[wi];
            a[k][0] = fmaf(wt, v0, a[k][0]);
            a[k][1] = fmaf(wt, v1, a[k][1]);
            a[k][2] = fmaf(wt, v2, a[k][2]);
            a[k][3] = fmaf(wt, v3, a[k][3]);
          }
        }
      }
    }
  }
  #pragma unroll
  for (int k = 0; k < 8; ++k) {
    a[k][0] = clip01(a[k][0]); a[k][1] = clip01(a[k][1]);
    a[k][2] = clip01(a[k][2]); a[k][3] = clip01(a[k][3]);
  }
  chain_quadN<8>(a, P, b, gx0, gy0, noise_u + plane, nlist, packed, out + plane);
}

// ---- fallback (ws too small): r3's fused single kernel ----
__global__ __launch_bounds__(256, 4)
void fallback_kernel(const float* __restrict__ x, const float* __restrict__ sigma_u,
                     const float* __restrict__ glare_u, const float* __restrict__ occ_u,
                     const float* __restrict__ rain_u, const float* __restrict__ rain_n_u,
                     const float* __restrict__ rain_alpha_u, const float* __restrict__ noise_u,
                     const float* __restrict__ noise_amt_u, const int* __restrict__ flags,
                     float* __restrict__ out)
{
  const int b = blockIdx.z, ch = blockIdx.y;
  const int ty0 = (blockIdx.x >> 3) * 64, tx0 = (blockIdx.x & 7) * 64;
  const int tid = threadIdx.x;
  const int f0 = flags[b * 5] > 0;
  PParams P = load_params(b, flags, glare_u, occ_u, rain_alpha_u, noise_amt_u);
  const float nrain = floorf(20.f + 41.f * rain_n_u[b]);
  const size_t plane = (size_t)(b * NC + ch) * PLN;
  const float* xp = x + plane;
  const float* np = noise_u + plane;
  float* op = out + plane;

  __shared__ __align__(16) float s_hb[88 * 64];

  float wr[KS];
  if (f0) {
    float sig = 1.f + 3.f * sigma_u[b];
    float ninv = -1.f / (2.f * sig * sig);
    float s = 0.f;
    #pragma unroll
    for (int t = 0; t < KS; ++t) {
      float d = (float)t - 12.f;
      wr[t] = __expf(d * d * ninv); s += wr[t];
    }
    float inv = 1.f / s;
    #pragma unroll
    for (int t = 0; t < KS; ++t) wr[t] *= inv;

    for (int i = tid; i < 88 * 16; i += 256) {
      int r = i >> 4, q = i & 15;
      int gy = ty0 + r - HALF;
      float a0 = 0.f, a1 = 0.f, a2 = 0.f, a3 = 0.f;
      if ((unsigned)gy < (unsigned)NH) {
        const float* rowp = xp + (size_t)gy * NW;
        int gx0 = tx0 + q * 4;
        float win[28];
        if (gx0 - HALF >= 0 && gx0 + 15 < NW) {
          #pragma unroll
          for (int j = 0; j < 7; ++j) {
            float4 v = *reinterpret_cast<const float4*>(rowp + gx0 - HALF + 4 * j);
            win[4 * j + 0] = v.x; win[4 * j + 1] = v.y;
            win[4 * j + 2] = v.z; win[4 * j + 3] = v.w;
          }
        } else {
          #pragma unroll
          for (int j = 0; j < 28; ++j) {
            int gx = gx0 - HALF + j;
            win[j] = ((unsigned)gx < (unsigned)NW) ? rowp[gx] : 0.f;
          }
        }
        #pragma unroll
        for (int t = 0; t < KS; ++t) {
          float wt = wr[t];
          a0 = fmaf(wt, win[t + 0], a0);
          a1 = fmaf(wt, win[t + 1], a1);
          a2 = fmaf(wt, win[t + 2], a2);
          a3 = fmaf(wt, win[t + 3], a3);
        }
      }
      *reinterpret_cast<float4*>(&s_hb[r * 64 + (i & 15) * 4]) =
          make_float4(a0, a1, a2, a3);
    }
    __syncthreads();
  }

  for (int i = tid; i < 512; i += 256) {
    int xq = i & 63, sy = i >> 6;
    int gx = tx0 + xq, gy0 = ty0 + sy * 8;
    float acc[8];
    if (f0) {
      float wincol[32];
      #pragma unroll
      for (int j = 0; j < 32; ++j) wincol[j] = s_hb[(sy * 8 + j) * 64 + xq];
      #pragma unroll
      for (int k = 0; k < 8; ++k) {
        float a = 0.f;
        #pragma unroll
        for (int t = 0; t < KS; ++t) a = fmaf(wr[t], wincol[k + t], a);
        acc[k] = clip01(a);
      }
    } else {
      #pragma unroll
      for (int k = 0; k < 8; ++k) acc[k] = xp[(size_t)(gy0 + k) * NW + gx];
    }
    const float fx = (float)gx;
    if (P.f1) {
      float dx = (fx - P.cx) * P.rxi;
      float dx2 = dx * dx;
      #pragma unroll
      for (int k = 0; k < 8; ++k) {
        float dy = ((float)(gy0 + k) - P.cy) * P.ryi;
        acc[k] = clip01(acc[k] + P.intensity * __expf(-(dx2 + dy * dy)));
      }
    }
    if (P.f2 && fx >= P.ox0 && fx < P.ox1) {
      #pragma unroll
      for (int k = 0; k < 8; ++k) {
        float fy = (float)(gy0 + k);
        if (fy >= P.oy0 && fy < P.oy1) acc[k] = 0.f;
      }
    }
    if (P.f3) {
      float cnt[8];
      #pragma unroll
      for (int k = 0; k < 8; ++k) cnt[k] = 0.f;
      for (int s = 0; s < NS; ++s) {
        if ((float)s < nrain) {
          float xc = floorf(rain_u[(b * NS + s) * 3 + 0] * 512.f);
          if (fx >= xc - 1.f && fx <= xc) {
            float y0 = floorf(rain_u[(b * NS + s) * 3 + 1] * 256.f);
            float y1 = 256.f + floorf(rain_u[(b * NS + s) * 3 + 2] * 256.f);
            #pragma unroll
            for (int k = 0; k < 8; ++k) {
              float fy = (float)(gy0 + k);
              cnt[k] += (fy >= y0 && fy < y1) ? 1.f : 0.f;
            }
          }
        }
      }
      #pragma unroll
      for (int k = 0; k < 8; ++k) {
        if (cnt[k] != 0.f) {
          float d = exp2f(cnt[k] * P.log1ma);
          acc[k] = clip01(acc[k] * d + (1.f - d));
        }
      }
    }
    if (P.f4) {
      #pragma unroll
      for (int k = 0; k < 8; ++k) {
        float nv = np[(size_t)(gy0 + k) * NW + gx];
        acc[k] = (nv < P.thr_lo) ? 0.f : ((nv > P.thr_hi) ? 1.f : acc[k]);
      }
    }
    #pragma unroll
    for (int k = 0; k < 8; ++k) op[(size_t)(gy0 + k) * NW + gx] = acc[k];
  }
}

extern "C" void kernel_launch(void* const* d_in, const int* in_sizes, int n_in,
                              void* d_out, int out_size, void* d_ws, size_t ws_size,
                              hipStream_t stream)
{
  const float* x            = (const float*)d_in[0];
  const float* sigma_u      = (const float*)d_in[1];
  const float* glare_u      = (const float*)d_in[2];
  const float* occ_u        = (const float*)d_in[3];
  const float* rain_u       = (const float*)d_in[4];
  const float* rain_n_u     = (const float*)d_in[5];
  const float* rain_alpha_u = (const float*)d_in[6];
  const float* noise_u      = (const float*)d_in[7];
  const float* noise_amt_u  = (const float*)d_in[8];
  const int*   flags        = (const int*)d_in[9];
  float* out = (float*)d_out;

  if (ws_size >= WS_NEED) {
    _Float16* hb     = (_Float16*)d_ws;
    float*    wts    = (float*)((char*)d_ws + WTS_OFF);
    int*      nlist  = (int*)((char*)d_ws + NL_OFF);
    unsigned* packed = (unsigned*)((char*)d_ws + PK_OFF);

    prep_kernel<<<65, 256, 0, stream>>>(rain_u, rain_n_u, sigma_u, nlist, packed, wts);
    k1_kernel<<<dim3(NH / 8, NC, NB), 256, 0, stream>>>(
        x, flags, wts, glare_u, occ_u, rain_alpha_u, noise_u, noise_amt_u,
        nlist, packed, hb, out);
    k2_kernel<<<3072, 256, 0, stream>>>(
        hb, wts, glare_u, occ_u, rain_alpha_u, noise_u, noise_amt_u,
        flags, nlist, packed, out);
  } else {
    dim3 grid(64, NC, NB);
    fallback_kernel<<<grid, 256, 0, stream>>>(
        x, sigma_u, glare_u, occ_u, rain_u, rain_n_u, rain_alpha_u,
        noise_u, noise_amt_u, flags, out);
  }
}

// Round 12
// 97.525 us; speedup vs baseline: 1.5547x; 1.2760x over previous
//
#include <hip/hip_runtime.h>

#define NB   32
#define NC   3
#define NH   512
#define NW   512
#define KS   25
#define HALF 12
#define NS   60
#define PLN  (NH * NW)        // 262144
#define NPL  (NB * NC)        // 96

typedef _Float16 half4 __attribute__((ext_vector_type(4)));
typedef _Float16 half8 __attribute__((ext_vector_type(8)));

// ---- workspace layout (hb fp16: 50.3 MB) ----
#define HB_BYTES  ((size_t)NPL * PLN * 2)
#define WTS_OFF   HB_BYTES
#define WTS_BYTES ((size_t)4096)
#define NL_OFF    (WTS_OFF + WTS_BYTES)
#define NL_BYTES  ((size_t)NB * NW * 4)
#define PK_OFF    (NL_OFF + NL_BYTES)
#define PK_BYTES  ((size_t)NB * NW * NS * 4)
#define WS_NEED   (PK_OFF + PK_BYTES)                 // ~54.3 MB

__device__ __forceinline__ float clip01(float v) { return fminf(fmaxf(v, 0.f), 1.f); }

struct PParams {
  int f1, f2, f3, f4;
  float intensity, cx, cy, rxi, ryi;
  float oy0, oy1, ox0, ox1;
  float log1ma;
  float thr_lo, thr_hi;
};

__device__ __forceinline__ PParams load_params(
    int b, const int* __restrict__ flags, const float* __restrict__ glare_u,
    const float* __restrict__ occ_u, const float* __restrict__ rain_alpha_u,
    const float* __restrict__ noise_amt_u)
{
  PParams P;
  P.f1 = flags[b * 5 + 1] > 0;
  P.f2 = flags[b * 5 + 2] > 0;
  P.f3 = flags[b * 5 + 3] > 0;
  P.f4 = flags[b * 5 + 4] > 0;
  float g0 = glare_u[b * 5 + 0], g1 = glare_u[b * 5 + 1], g2 = glare_u[b * 5 + 2],
        g3 = glare_u[b * 5 + 3], g4 = glare_u[b * 5 + 4];
  P.intensity = 0.4f + 0.5f * g0;
  P.rxi = 1.f / ((0.1f + 0.25f * g1) * 256.f);
  P.ryi = 1.f / ((0.1f + 0.25f * g2) * 256.f);
  P.cx = (0.2f + 0.6f * g3) * 512.f;
  P.cy = (0.2f + 0.6f * g4) * 512.f;
  float o0 = occ_u[b * 4 + 0], o1 = occ_u[b * 4 + 1],
        o2 = occ_u[b * 4 + 2], o3 = occ_u[b * 4 + 3];
  float ph = floorf(512.f * (0.1f + 0.3f * o0));
  float pw = floorf(512.f * (0.1f + 0.3f * o1));
  P.oy0 = floorf(o2 * (512.f - ph)); P.oy1 = P.oy0 + ph;
  P.ox0 = floorf(o3 * (512.f - pw)); P.ox1 = P.ox0 + pw;
  P.log1ma = log2f(1.f - (0.15f + 0.35f * rain_alpha_u[b]));
  float half_amt = 0.5f * (0.01f + 0.07f * noise_amt_u[b]);
  P.thr_lo = half_amt; P.thr_hi = 1.f - half_amt;
  return P;
}

// ---- prep: rain column lists + per-sample blur weights ----
__global__ void prep_kernel(const float* __restrict__ rain_u,
                            const float* __restrict__ rain_n_u,
                            const float* __restrict__ sigma_u,
                            int* __restrict__ nlist,
                            unsigned* __restrict__ packed,
                            float* __restrict__ wts)
{
  if (blockIdx.x == 64) {
    int b = threadIdx.x;
    if (b < NB) {
      float sig = 1.f + 3.f * sigma_u[b];
      float ninv = -1.f / (2.f * sig * sig);
      float w[KS]; float s = 0.f;
      #pragma unroll
      for (int j = 0; j < KS; ++j) {
        float d = (float)j - 12.f;
        w[j] = __expf(d * d * ninv);
        s += w[j];
      }
      float inv = 1.f / s;
      #pragma unroll
      for (int j = 0; j < KS; ++j) wts[b * 28 + j] = w[j] * inv;
    }
    return;
  }
  int t = blockIdx.x * 256 + threadIdx.x;
  if (t >= NB * NW) return;
  int b = t >> 9, wcol = t & 511;
  float n = floorf(20.f + 41.f * rain_n_u[b]);
  float wf = (float)wcol;
  int cnt = 0;
  for (int s = 0; s < NS; ++s) {
    if ((float)s < n) {
      float xc = floorf(rain_u[(b * NS + s) * 3 + 0] * 512.f);
      if (wf >= xc - 1.f && wf <= xc) {
        float y0 = floorf(rain_u[(b * NS + s) * 3 + 1] * 256.f);
        float y1 = 256.f + floorf(rain_u[(b * NS + s) * 3 + 2] * 256.f);
        packed[t * NS + cnt] = (((unsigned)y0) << 16) | (unsigned)y1;
        ++cnt;
      }
    }
  }
  nlist[t] = cnt;
}

// ---- chain on a 4-col x KR-row quad block ----
template<int KR>
__device__ __forceinline__ void chain_quadN(
    float (&a)[KR][4], const PParams& P, int b, int gx0, int gy0,
    const float* __restrict__ np_plane, const int* __restrict__ nlist,
    const unsigned* __restrict__ packed, float* __restrict__ op_plane)
{
  if (P.f1) {
    float dx2[4];
    #pragma unroll
    for (int c = 0; c < 4; ++c) {
      float dx = ((float)(gx0 + c) - P.cx) * P.rxi;
      dx2[c] = dx * dx;
    }
    #pragma unroll
    for (int k = 0; k < KR; ++k) {
      float dy = ((float)(gy0 + k) - P.cy) * P.ryi;
      float dy2 = dy * dy;
      #pragma unroll
      for (int c = 0; c < 4; ++c) {
        float g = __expf(-(dx2[c] + dy2));
        a[k][c] = clip01(a[k][c] + P.intensity * g);
      }
    }
  }
  if (P.f2) {
    #pragma unroll
    for (int c = 0; c < 4; ++c) {
      float fx = (float)(gx0 + c);
      if (fx >= P.ox0 && fx < P.ox1) {
        #pragma unroll
        for (int k = 0; k < KR; ++k) {
          float fy = (float)(gy0 + k);
          if (fy >= P.oy0 && fy < P.oy1) a[k][c] = 0.f;
        }
      }
    }
  }
  if (P.f3) {
    #pragma unroll
    for (int c = 0; c < 4; ++c) {
      int base = b * NW + gx0 + c;
      int n = nlist[base];
      if (n > 0) {
        float cnt[KR];
        #pragma unroll
        for (int k = 0; k < KR; ++k) cnt[k] = 0.f;
        for (int j = 0; j < n; ++j) {
          unsigned p = packed[base * NS + j];
          float y0 = (float)(p >> 16), y1 = (float)(p & 0xffffu);
          #pragma unroll
          for (int k = 0; k < KR; ++k) {
            float fy = (float)(gy0 + k);
            cnt[k] += (fy >= y0 && fy < y1) ? 1.f : 0.f;
          }
        }
        #pragma unroll
        for (int k = 0; k < KR; ++k) {
          if (cnt[k] != 0.f) {
            float d = exp2f(cnt[k] * P.log1ma);
            a[k][c] = clip01(a[k][c] * d + (1.f - d));
          }
        }
      }
    }
  }
  if (P.f4) {
    #pragma unroll
    for (int k = 0; k < KR; ++k) {
      float4 nv = *reinterpret_cast<const float4*>(
          np_plane + (size_t)(gy0 + k) * NW + gx0);
      a[k][0] = (nv.x < P.thr_lo) ? 0.f : ((nv.x > P.thr_hi) ? 1.f : a[k][0]);
      a[k][1] = (nv.y < P.thr_lo) ? 0.f : ((nv.y > P.thr_hi) ? 1.f : a[k][1]);
      a[k][2] = (nv.z < P.thr_lo) ? 0.f : ((nv.z > P.thr_hi) ? 1.f : a[k][2]);
      a[k][3] = (nv.w < P.thr_lo) ? 0.f : ((nv.w > P.thr_hi) ? 1.f : a[k][3]);
    }
  }
  #pragma unroll
  for (int k = 0; k < KR; ++k)
    *reinterpret_cast<float4*>(op_plane + (size_t)(gy0 + k) * NW + gx0) =
        make_float4(a[k][0], a[k][1], a[k][2], a[k][3]);
}

// ---- K1: blur samples -> h-blur (one WAVE = one row, branch-free: lane l
// computes cols 8l..8l+7 from 11 clamped float4 loads; zero-pad restored by
// 4 lane-fixup blocks). Non-blur samples -> streaming chain to out. r11's
// 4-output thread issued only 7 loads before a 100-FMA tail and had a
// divergent scalar edge path -> 1.5 TB/s. ----
__global__ __launch_bounds__(256, 4)
void k1_kernel(const float* __restrict__ x, const int* __restrict__ flags,
               const float* __restrict__ wts,
               const float* __restrict__ glare_u, const float* __restrict__ occ_u,
               const float* __restrict__ rain_alpha_u,
               const float* __restrict__ noise_u, const float* __restrict__ noise_amt_u,
               const int* __restrict__ nlist, const unsigned* __restrict__ packed,
               _Float16* __restrict__ hb, float* __restrict__ out)
{
  const int b = blockIdx.z, ch = blockIdx.y;
  const int tid = threadIdx.x;
  const int r0 = blockIdx.x << 3;              // 8 rows per block
  const size_t plane = (size_t)(b * NC + ch) * PLN;

  if (flags[b * 5] > 0) {
    // ---- h-blur: wave wv handles rows r0+wv and r0+wv+4 ----
    float w[KS];
    const float* wp = wts + b * 28;            // wave-uniform -> SGPRs
    #pragma unroll
    for (int j = 0; j < KS; ++j) w[j] = wp[j];

    const int lane = tid & 63, wv = tid >> 6;
    const int wstart = (lane << 3) - HALF;     // 8*lane - 12

    #pragma unroll
    for (int rr = 0; rr < 2; ++rr) {
      const int row = r0 + wv + (rr << 2);
      const float* rowp = x + plane + (size_t)row * NW;

      float win[44];
      #pragma unroll
      for (int j = 0; j < 11; ++j) {
        int col = wstart + 4 * j;
        col = max(0, min(col, NW - 4));        // clamp: safe addr, identity interior
        float4 v = *reinterpret_cast<const float4*>(rowp + col);
        win[4 * j + 0] = v.x; win[4 * j + 1] = v.y;
        win[4 * j + 2] = v.z; win[4 * j + 3] = v.w;
      }
      // zero-pad fixups (only lanes 0,1,62,63 carry out-of-range window slots)
      if (lane == 0) {
        #pragma unroll
        for (int i = 0; i < 12; ++i) win[i] = 0.f;
      }
      if (lane == 1) {
        #pragma unroll
        for (int i = 0; i < 4; ++i) win[i] = 0.f;
      }
      if (lane == 62) {
        #pragma unroll
        for (int i = 28; i < 44; ++i) win[i] = 0.f;
      }
      if (lane == 63) {
        #pragma unroll
        for (int i = 20; i < 44; ++i) win[i] = 0.f;
      }

      float acc[8];
      #pragma unroll
      for (int e = 0; e < 8; ++e) acc[e] = 0.f;
      #pragma unroll
      for (int t = 0; t < KS; ++t) {
        float wt = w[t];
        #pragma unroll
        for (int e = 0; e < 8; ++e) acc[e] = fmaf(wt, win[t + e], acc[e]);
      }
      half8 o;
      #pragma unroll
      for (int e = 0; e < 8; ++e) o[e] = (_Float16)acc[e];
      *reinterpret_cast<half8*>(hb + plane + (size_t)row * NW + (lane << 3)) = o;
    }
  } else {
    // ---- non-blur: streaming chain straight to out (4 rows/thread) ----
    PParams P = load_params(b, flags, glare_u, occ_u, rain_alpha_u, noise_amt_u);
    const int gx0 = (tid & 127) << 2;
    const int gy0 = r0 + ((tid >> 7) << 2);
    float a[4][4];
    const float* xp = x + plane + gx0;
    #pragma unroll
    for (int k = 0; k < 4; ++k) {
      float4 v = *reinterpret_cast<const float4*>(xp + (size_t)(gy0 + k) * NW);
      a[k][0] = v.x; a[k][1] = v.y; a[k][2] = v.z; a[k][3] = v.w;
    }
    chain_quadN<4>(a, P, b, gx0, gy0, noise_u + plane, nlist, packed, out + plane);
  }
}

// ---- K2: v-blur + chain, blur planes only. Balanced XCD swizzle (r11). ----
__global__ __launch_bounds__(256, 4)
void k2_kernel(const _Float16* __restrict__ hb, const float* __restrict__ wts,
               const float* __restrict__ glare_u, const float* __restrict__ occ_u,
               const float* __restrict__ rain_alpha_u,
               const float* __restrict__ noise_u, const float* __restrict__ noise_amt_u,
               const int* __restrict__ flags,
               const int* __restrict__ nlist, const unsigned* __restrict__ packed,
               float* __restrict__ out)
{
  const int lb = blockIdx.x;
  const int xcd = lb & 7, j = lb >> 3;
  const int pl = j >> 2, sub = j & 3;
  const int grp = (xcd + pl) & 7;
  const int strip = (grp << 2) | sub;         // 0..31
  const int b = pl / 3;
  if (flags[b * 5] <= 0) return;

  const int tid = threadIdx.x;
  const int gy0 = strip * 16 + ((tid >> 7) << 3);
  const int gx0 = (tid & 127) << 2;
  PParams P = load_params(b, flags, glare_u, occ_u, rain_alpha_u, noise_amt_u);
  const size_t plane = (size_t)pl * PLN;

  float w[KS];
  const float* wp = wts + b * 28;
  #pragma unroll
  for (int jj = 0; jj < KS; ++jj) w[jj] = wp[jj];

  float a[8][4];
  #pragma unroll
  for (int k = 0; k < 8; ++k) {
    a[k][0] = 0.f; a[k][1] = 0.f; a[k][2] = 0.f; a[k][3] = 0.f;
  }
  if (gy0 >= 16 && gy0 <= 488) {
    const _Float16* hp0 = hb + plane + (size_t)(gy0 - HALF) * NW + gx0;
    #pragma unroll
    for (int m = 0; m < 32; ++m) {
      half4 v = *reinterpret_cast<const half4*>(hp0 + (size_t)m * NW);
      float v0 = (float)v.x, v1 = (float)v.y, v2 = (float)v.z, v3 = (float)v.w;
      #pragma unroll
      for (int k = 0; k < 8; ++k) {
        int wi = m - k;
        if (wi >= 0 && wi <= 24) {
          float wt = w[wi];
          a[k][0] = fmaf(wt, v0, a[k][0]);
          a[k][1] = fmaf(wt, v1, a[k][1]);
          a[k][2] = fmaf(wt, v2, a[k][2]);
          a[k][3] = fmaf(wt, v3, a[k][3]);
        }
      }
    }
  } else {
    const _Float16* hp = hb + plane + gx0;
    #pragma unroll
    for (int m = 0; m < 32; ++m) {
      int gy = gy0 - HALF + m;
      if ((unsigned)gy < (unsigned)NH) {
        half4 v = *reinterpret_cast<const half4*>(hp + (size_t)gy * NW);
        float v0 = (float)v.x, v1 = (float)v.y, v2 = (float)v.z, v3 = (float)v.w;
        #pragma unroll
        for (int k = 0; k < 8; ++k) {
          int wi = m - k;
          if (wi >= 0 && wi <= 24) {
            float wt = w[wi];
            a[k][0] = fmaf(wt, v0, a[k][0]);
            a[k][1] = fmaf(wt, v1, a[k][1]);
            a[k][2] = fmaf(wt, v2, a[k][2]);
            a[k][3] = fmaf(wt, v3, a[k][3]);
          }
        }
      }
    }
  }
  #pragma unroll
  for (int k = 0; k < 8; ++k) {
    a[k][0] = clip01(a[k][0]); a[k][1] = clip01(a[k][1]);
    a[k][2] = clip01(a[k][2]); a[k][3] = clip01(a[k][3]);
  }
  chain_quadN<8>(a, P, b, gx0, gy0, noise_u + plane, nlist, packed, out + plane);
}

// ---- fallback (ws too small): r3's fused single kernel ----
__global__ __launch_bounds__(256, 4)
void fallback_kernel(const float* __restrict__ x, const float* __restrict__ sigma_u,
                     const float* __restrict__ glare_u, const float* __restrict__ occ_u,
                     const float* __restrict__ rain_u, const float* __restrict__ rain_n_u,
                     const float* __restrict__ rain_alpha_u, const float* __restrict__ noise_u,
                     const float* __restrict__ noise_amt_u, const int* __restrict__ flags,
                     float* __restrict__ out)
{
  const int b = blockIdx.z, ch = blockIdx.y;
  const int ty0 = (blockIdx.x >> 3) * 64, tx0 = (blockIdx.x & 7) * 64;
  const int tid = threadIdx.x;
  const int f0 = flags[b * 5] > 0;
  PParams P = load_params(b, flags, glare_u, occ_u, rain_alpha_u, noise_amt_u);
  const float nrain = floorf(20.f + 41.f * rain_n_u[b]);
  const size_t plane = (size_t)(b * NC + ch) * PLN;
  const float* xp = x + plane;
  const float* np = noise_u + plane;
  float* op = out + plane;

  __shared__ __align__(16) float s_hb[88 * 64];

  float wr[KS];
  if (f0) {
    float sig = 1.f + 3.f * sigma_u[b];
    float ninv = -1.f / (2.f * sig * sig);
    float s = 0.f;
    #pragma unroll
    for (int t = 0; t < KS; ++t) {
      float d = (float)t - 12.f;
      wr[t] = __expf(d * d * ninv); s += wr[t];
    }
    float inv = 1.f / s;
    #pragma unroll
    for (int t = 0; t < KS; ++t) wr[t] *= inv;

    for (int i = tid; i < 88 * 16; i += 256) {
      int r = i >> 4, q = i & 15;
      int gy = ty0 + r - HALF;
      float a0 = 0.f, a1 = 0.f, a2 = 0.f, a3 = 0.f;
      if ((unsigned)gy < (unsigned)NH) {
        const float* rowp = xp + (size_t)gy * NW;
        int gx0 = tx0 + q * 4;
        float win[28];
        if (gx0 - HALF >= 0 && gx0 + 15 < NW) {
          #pragma unroll
          for (int j = 0; j < 7; ++j) {
            float4 v = *reinterpret_cast<const float4*>(rowp + gx0 - HALF + 4 * j);
            win[4 * j + 0] = v.x; win[4 * j + 1] = v.y;
            win[4 * j + 2] = v.z; win[4 * j + 3] = v.w;
          }
        } else {
          #pragma unroll
          for (int j = 0; j < 28; ++j) {
            int gx = gx0 - HALF + j;
            win[j] = ((unsigned)gx < (unsigned)NW) ? rowp[gx] : 0.f;
          }
        }
        #pragma unroll
        for (int t = 0; t < KS; ++t) {
          float wt = wr[t];
          a0 = fmaf(wt, win[t + 0], a0);
          a1 = fmaf(wt, win[t + 1], a1);
          a2 = fmaf(wt, win[t + 2], a2);
          a3 = fmaf(wt, win[t + 3], a3);
        }
      }
      *reinterpret_cast<float4*>(&s_hb[r * 64 + (i & 15) * 4]) =
          make_float4(a0, a1, a2, a3);
    }
    __syncthreads();
  }

  for (int i = tid; i < 512; i += 256) {
    int xq = i & 63, sy = i >> 6;
    int gx = tx0 + xq, gy0 = ty0 + sy * 8;
    float acc[8];
    if (f0) {
      float wincol[32];
      #pragma unroll
      for (int j = 0; j < 32; ++j) wincol[j] = s_hb[(sy * 8 + j) * 64 + xq];
      #pragma unroll
      for (int k = 0; k < 8; ++k) {
        float a = 0.f;
        #pragma unroll
        for (int t = 0; t < KS; ++t) a = fmaf(wr[t], wincol[k + t], a);
        acc[k] = clip01(a);
      }
    } else {
      #pragma unroll
      for (int k = 0; k < 8; ++k) acc[k] = xp[(size_t)(gy0 + k) * NW + gx];
    }
    const float fx = (float)gx;
    if (P.f1) {
      float dx = (fx - P.cx) * P.rxi;
      float dx2 = dx * dx;
      #pragma unroll
      for (int k = 0; k < 8; ++k) {
        float dy = ((float)(gy0 + k) - P.cy) * P.ryi;
        acc[k] = clip01(acc[k] + P.intensity * __expf(-(dx2 + dy * dy)));
      }
    }
    if (P.f2 && fx >= P.ox0 && fx < P.ox1) {
      #pragma unroll
      for (int k = 0; k < 8; ++k) {
        float fy = (float)(gy0 + k);
        if (fy >= P.oy0 && fy < P.oy1) acc[k] = 0.f;
      }
    }
    if (P.f3) {
      float cnt[8];
      #pragma unroll
      for (int k = 0; k < 8; ++k) cnt[k] = 0.f;
      for (int s = 0; s < NS; ++s) {
        if ((float)s < nrain) {
          float xc = floorf(rain_u[(b * NS + s) * 3 + 0] * 512.f);
          if (fx >= xc - 1.f && fx <= xc) {
            float y0 = floorf(rain_u[(b * NS + s) * 3 + 1] * 256.f);
            float y1 = 256.f + floorf(rain_u[(b * NS + s) * 3 + 2] * 256.f);
            #pragma unroll
            for (int k = 0; k < 8; ++k) {
              float fy = (float)(gy0 + k);
              cnt[k] += (fy >= y0 && fy < y1) ? 1.f : 0.f;
            }
          }
        }
      }
      #pragma unroll
      for (int k = 0; k < 8; ++k) {
        if (cnt[k] != 0.f) {
          float d = exp2f(cnt[k] * P.log1ma);
          acc[k] = clip01(acc[k] * d + (1.f - d));
        }
      }
    }
    if (P.f4) {
      #pragma unroll
      for (int k = 0; k < 8; ++k) {
        float nv = np[(size_t)(gy0 + k) * NW + gx];
        acc[k] = (nv < P.thr_lo) ? 0.f : ((nv > P.thr_hi) ? 1.f : acc[k]);
      }
    }
    #pragma unroll
    for (int k = 0; k < 8; ++k) op[(size_t)(gy0 + k) * NW + gx] = acc[k];
  }
}

extern "C" void kernel_launch(void* const* d_in, const int* in_sizes, int n_in,
                              void* d_out, int out_size, void* d_ws, size_t ws_size,
                              hipStream_t stream)
{
  const float* x            = (const float*)d_in[0];
  const float* sigma_u      = (const float*)d_in[1];
  const float* glare_u      = (const float*)d_in[2];
  const float* occ_u        = (const float*)d_in[3];
  const float* rain_u       = (const float*)d_in[4];
  const float* rain_n_u     = (const float*)d_in[5];
  const float* rain_alpha_u = (const float*)d_in[6];
  const float* noise_u      = (const float*)d_in[7];
  const float* noise_amt_u  = (const float*)d_in[8];
  const int*   flags        = (const int*)d_in[9];
  float* out = (float*)d_out;

  if (ws_size >= WS_NEED) {
    _Float16* hb     = (_Float16*)d_ws;
    float*    wts    = (float*)((char*)d_ws + WTS_OFF);
    int*      nlist  = (int*)((char*)d_ws + NL_OFF);
    unsigned* packed = (unsigned*)((char*)d_ws + PK_OFF);

    prep_kernel<<<65, 256, 0, stream>>>(rain_u, rain_n_u, sigma_u, nlist, packed, wts);
    k1_kernel<<<dim3(NH / 8, NC, NB), 256, 0, stream>>>(
        x, flags, wts, glare_u, occ_u, rain_alpha_u, noise_u, noise_amt_u,
        nlist, packed, hb, out);
    k2_kernel<<<3072, 256, 0, stream>>>(
        hb, wts, glare_u, occ_u, rain_alpha_u, noise_u, noise_amt_u,
        flags, nlist, packed, out);
  } else {
    dim3 grid(64, NC, NB);
    fallback_kernel<<<grid, 256, 0, stream>>>(
        x, sigma_u, glare_u, occ_u, rain_u, rain_n_u, rain_alpha_u,
        noise_u, noise_amt_u, flags, out);
  }
}